// Round 13
// baseline (166.722 us; speedup 1.0000x reference)
//
#include <hip/hip_runtime.h>

#define NB   1024
#define NN   128
#define NOBS 64
#define NHID 128
#define NACT 9
#define NTHR 512
#define WLD  136   // padded LDS row stride in halves: conflict-free b128 column reads
#define CVS2 20    // CV row stride in dwords

// workspace offsets (fp16 elements): [hi | lo] per weight, transposed to [dout_pad][din]
#define OFF_ENC 0
#define OFF_V   16384
#define OFF_K   49152
#define OFF_Q   81920
#define OFF_W1  114688
#define OFF_W2  147456
#define OFF_W3  180224
#define OFF_W4  212992

typedef __attribute__((ext_vector_type(8))) _Float16 half8;
typedef __attribute__((ext_vector_type(4))) _Float16 half4v;
typedef __attribute__((ext_vector_type(2))) __fp16 fp16x2;
typedef __attribute__((ext_vector_type(4))) float f32x4;

union H8 { half8 v; fp16x2 p[4]; };
union H4 { half4v v; fp16x2 p[2]; };

// ---------- weight prep: fp16 hi/lo split (RNE), transposed [dout_pad][din] ----------
__global__ void prep_w(const float* __restrict__ w, _Float16* __restrict__ hi,
                       _Float16* __restrict__ lo, int din, int dout, int dpad){
  int i = blockIdx.x * blockDim.x + threadIdx.x;
  if (i >= dpad * din) return;
  int c = i / din, k = i - c * din;
  float v = (c < dout) ? w[(size_t)k * dout + c] : 0.0f;
  _Float16 h = (_Float16)v;
  hi[i] = h;
  lo[i] = (_Float16)(v - (float)h);
}

// ---------- activation split: 8 f32 -> fp16 hi/lo fragments via packed RTZ converts ----------
__device__ __forceinline__ void pack_split8(const float* fv, half8& ah, half8& al){
  H8 A, L;
#pragma unroll
  for (int j = 0; j < 4; ++j){
    fp16x2 h = __builtin_amdgcn_cvt_pkrtz(fv[2*j], fv[2*j+1]);
    float r0 = fv[2*j]   - (float)h[0];
    float r1 = fv[2*j+1] - (float)h[1];
    A.p[j] = h;
    L.p[j] = __builtin_amdgcn_cvt_pkrtz(r0, r1);
  }
  ah = A.v; al = L.v;
}

// ---------- threefry2x32, key = (0, 42) ----------
__device__ __forceinline__ void tf4(unsigned& v0, unsigned& v1, int r0,int r1,int r2,int r3){
  v0 += v1; v1 = (v1<<r0)|(v1>>(32-r0)); v1 ^= v0;
  v0 += v1; v1 = (v1<<r1)|(v1>>(32-r1)); v1 ^= v0;
  v0 += v1; v1 = (v1<<r2)|(v1>>(32-r2)); v1 ^= v0;
  v0 += v1; v1 = (v1<<r3)|(v1>>(32-r3)); v1 ^= v0;
}
__device__ __forceinline__ void threefry(unsigned x0, unsigned x1, unsigned& o0, unsigned& o1){
  const unsigned ks0 = 0u, ks1 = 42u, ks2 = 0x1BD11BDAu ^ 0u ^ 42u;
  unsigned v0 = x0 + ks0, v1 = x1 + ks1;
  tf4(v0,v1,13,15,26,6);  v0 += ks1; v1 += ks2 + 1u;
  tf4(v0,v1,17,29,16,24); v0 += ks2; v1 += ks0 + 2u;
  tf4(v0,v1,13,15,26,6);  v0 += ks0; v1 += ks1 + 3u;
  tf4(v0,v1,17,29,16,24); v0 += ks1; v1 += ks2 + 4u;
  tf4(v0,v1,13,15,26,6);  v0 += ks2; v1 += ks0 + 5u;
  o0 = v0; o1 = v1;
}

#define MFMA(a,b,c) __builtin_amdgcn_mfma_f32_16x16x32_f16((a),(b),(c),0,0,0)
// 3-term split product: ah*bh + al*bh + ah*bl  (al*bl ~ 2^-22, omitted)
#define MFMA3(ah,al,bh,bl,c) do{ (c)=MFMA((ah),(bh),(c)); (c)=MFMA((al),(bh),(c)); \
                                 (c)=MFMA((ah),(bl),(c)); }while(0)

__device__ __forceinline__ void zero8(f32x4* a){
#pragma unroll
  for (int c = 0; c < 8; ++c) a[c] = (f32x4){0.f,0.f,0.f,0.f};
}
// bias preload (coalesced; issued early so latency hides under prior compute)
__device__ __forceinline__ void load_bias8(const float* __restrict__ bias, int l15, float* bb){
#pragma unroll
  for (int c = 0; c < 8; ++c) bb[c] = bias[16*c + l15];
}
// acc init = bias (replaces zero-init + epilogue add)
__device__ __forceinline__ void init8(f32x4* a, const float* bb){
#pragma unroll
  for (int c = 0; c < 8; ++c) a[c] = (f32x4){bb[c], bb[c], bb[c], bb[c]};
}
__device__ __forceinline__ void relu8(f32x4* a){
#pragma unroll
  for (int c = 0; c < 8; ++c)
#pragma unroll
    for (int i = 0; i < 4; ++i) a[c][i] = fmaxf(a[c][i], 0.0f);
}

// ---------- async stage: issue global->reg early, write reg->LDS after barrier ----------
template<int NG>
__device__ __forceinline__ void stage_load(const _Float16* __restrict__ src, int loOff,
                                           half8* bh, half8* bl, int tid){
#pragma unroll
  for (int j = 0; j*NTHR < NG; ++j){
    int t = j*NTHR + tid;
    if (NG % NTHR != 0 && t >= NG) break;
    bh[j] = *(const half8*)(src + t*8);
    bl[j] = *(const half8*)(src + loOff + t*8);
  }
}
template<int NG, int GPR>
__device__ __forceinline__ void stage_write(const half8* bh, const half8* bl,
                                            _Float16* dsth, _Float16* dstl, int tid){
#pragma unroll
  for (int j = 0; j*NTHR < NG; ++j){
    int t = j*NTHR + tid;
    if (NG % NTHR != 0 && t >= NG) break;
    int row = t / GPR, gc = t - row*GPR;
    int d = row*WLD + gc*8;
    *(half8*)(dsth + d) = bh[j];
    *(half8*)(dstl + d) = bl[j];
  }
}

// dense GEMM: A-frags in regs, B in LDS padded [rows][WLD] hi/lo; setprio'd MFMA cluster
template<int K>
__device__ __forceinline__ void gemm_lds(const half8* fh, const half8* fl,
                                         const _Float16* SWh, const _Float16* SWl,
                                         f32x4* acc, int g, int l15){
  __builtin_amdgcn_s_setprio(1);
#pragma unroll
  for (int kp = 0; kp < K/32; ++kp){
#pragma unroll
    for (int c = 0; c < 8; ++c){
      const int idx = (16*c + l15)*WLD + (4*kp + g)*8;
      half8 bh = *(const half8*)(SWh + idx);
      half8 bl = *(const half8*)(SWl + idx);
      MFMA3(fh[kp], fl[kp], bh, bl, acc[c]);
    }
  }
  __builtin_amdgcn_s_setprio(0);
}

// acc chunk kp -> this lane's row-major 8 f32 (row l15, cols 8g..8g+7) via wave-private CV
__device__ __forceinline__ void cv_row8(const f32x4* pa, int kp, float* CVf,
                                        int g, int l15, float* fv){
  const int roff = l15*CVS2 + 8*(g & 1);
#pragma unroll
  for (int i = 0; i < 4; ++i) CVf[(4*g+i)*CVS2 + l15] = pa[2*kp][i];
  f32x4 a0 = *(const f32x4*)(CVf + roff);
  f32x4 a1 = *(const f32x4*)(CVf + roff + 4);
#pragma unroll
  for (int i = 0; i < 4; ++i) CVf[(4*g+i)*CVS2 + l15] = pa[2*kp+1][i];
  f32x4 b0 = *(const f32x4*)(CVf + roff);
  f32x4 b1 = *(const f32x4*)(CVf + roff + 4);
  f32x4 f0 = (g < 2) ? a0 : b0;
  f32x4 f1 = (g < 2) ? a1 : b1;
  fv[0]=f0[0]; fv[1]=f0[1]; fv[2]=f0[2]; fv[3]=f0[3];
  fv[4]=f1[0]; fv[5]=f1[1]; fv[6]=f1[2]; fv[7]=f1[3];
}

// full acc -> 4 fragment pairs
__device__ __forceinline__ void conv_all16(const f32x4* pa, float* CVf, int g, int l15,
                                           half8* fh, half8* fl){
#pragma unroll
  for (int kp = 0; kp < 4; ++kp){
    float fv[8];
    cv_row8(pa, kp, CVf, g, l15, fv);
    pack_split8(fv, fh[kp], fl[kp]);
  }
}

// fused conv + GEMM: per kp, convert A chunk then immediately run its 24 MFMAs
__device__ __forceinline__ void gemm_cv(const f32x4* pa, float* CVf,
                                        const _Float16* SWh, const _Float16* SWl,
                                        f32x4* acc, int g, int l15){
#pragma unroll
  for (int kp = 0; kp < 4; ++kp){
    float fv[8];
    cv_row8(pa, kp, CVf, g, l15, fv);
    half8 ah, al;
    pack_split8(fv, ah, al);
    __builtin_amdgcn_s_setprio(1);
#pragma unroll
    for (int c = 0; c < 8; ++c){
      const int idx = (16*c + l15)*WLD + (4*kp + g)*8;
      half8 bh = *(const half8*)(SWh + idx);
      half8 bl = *(const half8*)(SWl + idx);
      MFMA3(ah, al, bh, bl, acc[c]);
    }
    __builtin_amdgcn_s_setprio(0);
  }
}

__global__ void __launch_bounds__(NTHR)
dgn_main(const float* __restrict__ x, const float* __restrict__ mask,
         const _Float16* __restrict__ wt,
         const float* __restrict__ encb, const float* __restrict__ bv,
         const float* __restrict__ bk, const float* __restrict__ bq,
         const float* __restrict__ b1, const float* __restrict__ b2,
         const float* __restrict__ b3, const float* __restrict__ b4,
         float* __restrict__ out){
  // static LDS: 2*34816 + 10240 = 79872 B -> 2 blocks/CU
  __shared__ __align__(16) _Float16 SHh[128*WLD];
  __shared__ __align__(16) _Float16 SHl[128*WLD];
  __shared__ __align__(16) float CVA[8*16*CVS2];

  const int tid  = threadIdx.x;
  const int lane = tid & 63;
  const int w    = tid >> 6;
  const int l15  = lane & 15;
  const int g    = lane >> 4;
  const int b    = blockIdx.x;
  float* CVf = CVA + w*16*CVS2;

  f32x4 accA[8], accB[8];
  half8 wbh[4], wbl[4];   // async weight staging buffer
  float bb[8];            // next-layer bias, preloaded

  // ---- P0: issue x loads FIRST (HBM latency hides under enc staging), then enc async stage
  const float* xrow = x + ((size_t)b*NN + w*16 + l15)*NOBS;
  float4 xf[4];
  xf[0] = *(const float4*)(xrow + 8*g);
  xf[1] = *(const float4*)(xrow + 8*g + 4);
  xf[2] = *(const float4*)(xrow + 32 + 8*g);
  xf[3] = *(const float4*)(xrow + 32 + 8*g + 4);
  load_bias8(encb, l15, bb);
  stage_load<1024>(wt + OFF_ENC, 8192, wbh, wbl, tid);
  stage_write<1024,8>(wbh, wbl, SHh, SHl, tid);
  __syncthreads();                                   // B1 enc ready

  // ---- P1: h1 = relu(x @ enc_w + enc_b); prefetch Wq + bq
  init8(accA, bb);
  stage_load<2048>(wt + OFF_Q, 16384, wbh, wbl, tid);
  load_bias8(bq, l15, bb);
  {
    half8 xh[2], xl[2];
    float fv0[8] = {xf[0].x,xf[0].y,xf[0].z,xf[0].w,xf[1].x,xf[1].y,xf[1].z,xf[1].w};
    float fv1[8] = {xf[2].x,xf[2].y,xf[2].z,xf[2].w,xf[3].x,xf[3].y,xf[3].z,xf[3].w};
    pack_split8(fv0, xh[0], xl[0]);
    pack_split8(fv1, xh[1], xl[1]);
    gemm_lds<NOBS>(xh, xl, SHh, SHl, accA, g, l15);
  }
  relu8(accA);
  half8 h1h[4], h1l[4];
  conv_all16(accA, CVf, g, l15, h1h, h1l);           // wave-private CV: safe pre-barrier
  __syncthreads();                                   // B2 enc reads done
  stage_write<2048,16>(wbh, wbl, SHh, SHl, tid);
  __syncthreads();                                   // B3 Wq ready

  // ---- P2: q = relu(h1 @ wq + bq); prefetch Wk + bk
  init8(accA, bb);
  stage_load<2048>(wt + OFF_K, 16384, wbh, wbl, tid);
  load_bias8(bk, l15, bb);
  gemm_lds<NHID>(h1h, h1l, SHh, SHl, accA, g, l15);
  relu8(accA);
  half8 qfh[4], qfl[4];
  conv_all16(accA, CVf, g, l15, qfh, qfl);
  __syncthreads();                                   // B4 Wq reads done
  stage_write<2048,16>(wbh, wbl, SHh, SHl, tid);
  __syncthreads();                                   // B5 Wk ready

  // ---- P3: prefetch mask; k = relu(h1 @ wk + bk) -> split straight into SH
  float mpre[32];
  {
    const float* mbase = mask + (size_t)b*NN*NN;
#pragma unroll
    for (int c = 0; c < 8; ++c)
#pragma unroll
      for (int i = 0; i < 4; ++i)
        mpre[c*4+i] = mbase[(w*16 + 4*g + i)*NN + 16*c + l15];
  }
  init8(accA, bb);
  gemm_lds<NHID>(h1h, h1l, SHh, SHl, accA, g, l15);
  relu8(accA);
  __syncthreads();                                   // B6 Wk reads done (all waves)
#pragma unroll
  for (int c = 0; c < 8; ++c)
#pragma unroll
    for (int i = 0; i < 4; ++i){
      float v = accA[c][i];
      _Float16 kh = (_Float16)v;
      const int idx = (w*16 + 4*g + i)*WLD + 16*c + l15;
      SHh[idx] = kh;
      SHl[idx] = (_Float16)(v - (float)kh);
    }
  __syncthreads();                                   // B7 k staged

  // ---- P4: scores = q @ k^T
  zero8(accB);
  gemm_lds<NHID>(qfh, qfl, SHh, SHl, accB, g, l15);
  __syncthreads();                                   // B8 k reads done

  // ---- P5: mask/clip -> h out, row-softmax, att frags; Wv + bv prefetched under softmax
  half8 afh[4], afl[4];
  {
    float* hbase = out + (size_t)NB*NN + (size_t)b*NN*NN;
    float mx[4] = {-3.0e38f,-3.0e38f,-3.0e38f,-3.0e38f};
#pragma unroll
    for (int c = 0; c < 8; ++c)
#pragma unroll
      for (int i = 0; i < 4; ++i){
        const int row = w*16 + 4*g + i, col = 16*c + l15;
        float m = mpre[c*4+i];
        float hvv = fminf(fmaxf(accB[c][i]*m, 0.0f), 9.0e13f) - 9.0e15f*(1.0f - m);
        hbase[row*NN + col] = hvv;
        accB[c][i] = hvv;
        mx[i] = fmaxf(mx[i], hvv);
      }
    stage_load<2048>(wt + OFF_V, 16384, wbh, wbl, tid);
    load_bias8(bv, l15, bb);
#pragma unroll
    for (int off = 8; off >= 1; off >>= 1)
#pragma unroll
      for (int i = 0; i < 4; ++i) mx[i] = fmaxf(mx[i], __shfl_xor(mx[i], off, 64));
    float sm[4] = {0.f,0.f,0.f,0.f};
#pragma unroll
    for (int c = 0; c < 8; ++c)
#pragma unroll
      for (int i = 0; i < 4; ++i){
        float e = __expf(accB[c][i] - mx[i]);
        accB[c][i] = e; sm[i] += e;
      }
#pragma unroll
    for (int off = 8; off >= 1; off >>= 1)
#pragma unroll
      for (int i = 0; i < 4; ++i) sm[i] += __shfl_xor(sm[i], off, 64);
    float inv[4];
#pragma unroll
    for (int i = 0; i < 4; ++i) inv[i] = 16384.0f / sm[i];  // 2^14 denorm guard
#pragma unroll
    for (int c = 0; c < 8; ++c)
#pragma unroll
      for (int i = 0; i < 4; ++i) accB[c][i] *= inv[i];
    conv_all16(accB, CVf, g, l15, afh, afl);
  }
  stage_write<2048,16>(wbh, wbl, SHh, SHl, tid);
  __syncthreads();                                   // B9 Wv ready

  // ---- P6: v = relu(h1 @ wv + bv); h1 dies
  init8(accA, bb);
  gemm_lds<NHID>(h1h, h1l, SHh, SHl, accA, g, l15);
  relu8(accA);
  __syncthreads();                                   // B10 Wv reads done (all waves)

  // ---- P7: stage vT (transposed, packed converts, b64 stores)
#pragma unroll
  for (int c = 0; c < 8; ++c){
    H4 hp, lp;
#pragma unroll
    for (int j = 0; j < 2; ++j){
      float v0 = accA[c][2*j], v1 = accA[c][2*j+1];
      fp16x2 h = __builtin_amdgcn_cvt_pkrtz(v0, v1);
      hp.p[j] = h;
      lp.p[j] = __builtin_amdgcn_cvt_pkrtz(v0 - (float)h[0], v1 - (float)h[1]);
    }
    const int idx = (16*c + l15)*WLD + w*16 + 4*g;
    *(half4v*)(SHh + idx) = hp.v;
    *(half4v*)(SHl + idx) = lp.v;
  }
  __syncthreads();                                   // B11 vT staged

  // ---- P8: h2 = att @ v (scaled); prefetch W1 + b1
  stage_load<2048>(wt + OFF_W1, 16384, wbh, wbl, tid);
  load_bias8(b1, l15, bb);
  zero8(accB);
  gemm_lds<NHID>(afh, afl, SHh, SHl, accB, g, l15);
#pragma unroll
  for (int c = 0; c < 8; ++c)
#pragma unroll
    for (int i = 0; i < 4; ++i) accB[c][i] *= 6.103515625e-05f;  // 2^-14
  __syncthreads();                                   // B12 vT reads done
  stage_write<2048,16>(wbh, wbl, SHh, SHl, tid);
  __syncthreads();                                   // B13 W1 ready

  // ---- P9: MLP chain, fused conv+gemm, async staging, bias-init accs
  init8(accA, bb);                                   // b1
  stage_load<2048>(wt + OFF_W2, 16384, wbh, wbl, tid);
  load_bias8(b2, l15, bb);
  gemm_cv(accB, CVf, SHh, SHl, accA, g, l15);        // a1 = h2 @ W1 + b1
  relu8(accA);
  __syncthreads();                                   // B14 W1 reads done
  stage_write<2048,16>(wbh, wbl, SHh, SHl, tid);
  __syncthreads();                                   // B15 W2 ready

  init8(accB, bb);                                   // b2
  stage_load<2048>(wt + OFF_W3, 16384, wbh, wbl, tid);
  load_bias8(b3, l15, bb);
  float b4v = (l15 < NACT) ? b4[l15] : 0.0f;
  gemm_cv(accA, CVf, SHh, SHl, accB, g, l15);        // a2 = a1 @ W2 + b2
  relu8(accB);
  __syncthreads();                                   // B16 W2 reads done
  stage_write<2048,16>(wbh, wbl, SHh, SHl, tid);
  __syncthreads();                                   // B17 W3 ready

  init8(accA, bb);                                   // b3
  gemm_cv(accB, CVf, SHh, SHl, accA, g, l15);        // a3 = a2 @ W3 + b3
  relu8(accA);
  // no barrier: W4 is read from global (L2), SH untouched afterwards

  // ---- P10: logits = a3 @ w4 + b4 (W4 direct from L2; fused conv)
  f32x4 la = (f32x4){b4v, b4v, b4v, b4v};
#pragma unroll
  for (int kp = 0; kp < 4; ++kp){
    float fv[8];
    cv_row8(accA, kp, CVf, g, l15, fv);
    half8 ah, al;
    pack_split8(fv, ah, al);
    const int wof = l15*NHID + (4*kp + g)*8;
    half8 bh = *(const half8*)(wt + OFF_W4 + wof);
    half8 bl = *(const half8*)(wt + OFF_W4 + 2048 + wof);
    MFMA3(ah, al, bh, bl, la);
  }
#pragma unroll
  for (int i = 0; i < 4; ++i)
    CVf[(4*g+i)*CVS2 + l15] = la[i];

  // ---- P11: threefry-gumbel + argmax(gumbel + logits), wave-parallel
  // argmax(g + log softmax(L)) == argmax(g + L) (per-row constant shift).
  // Lane (g,l15): row = l15, candidates c = g + 4j (j=0..2, c<9); 2-step shfl reduce.
  {
    const int R = b*NN + w*16 + l15;
    const unsigned HHALF = (unsigned)(NB*NN*NACT/2);  // 589824
    float best = -3.0e38f; int bi = NACT;
#pragma unroll
    for (int j = 0; j < 3; ++j){
      const int c = g + 4*j;
      if (c < NACT){
        float lg = CVf[l15*CVS2 + c];
        unsigned e = (unsigned)(R*NACT + c);
        unsigned c0 = (e < HHALF) ? e : (e - HHALF);
        unsigned o0, o1; threefry(c0, c0 + HHALF, o0, o1);
        unsigned bits = (e < HHALF) ? o0 : o1;
        float u = __uint_as_float((bits >> 9) | 0x3f800000u) - 1.0f;
        float uu = fmaxf(1.17549435e-38f, u + 1.17549435e-38f);
        float gmb = -logf(-logf(uu));
        float scv = gmb + lg;
        if (scv > best){ best = scv; bi = c; }      // within-lane c ascending -> first max
      }
    }
#pragma unroll
    for (int off = 16; off <= 32; off <<= 1){
      float ov = __shfl_xor(best, off, 64);
      int   oi = __shfl_xor(bi,   off, 64);
      if (ov > best || (ov == best && oi < bi)){ best = ov; bi = oi; }
    }
    if (g == 0) out[R] = (float)bi;
  }
}

extern "C" void kernel_launch(void* const* d_in, const int* in_sizes, int n_in,
                              void* d_out, int out_size, void* d_ws, size_t ws_size,
                              hipStream_t stream){
  const float* x     = (const float*)d_in[0];
  const float* mask  = (const float*)d_in[1];
  const float* enc_w = (const float*)d_in[2];
  const float* enc_b = (const float*)d_in[3];
  const float* wv    = (const float*)d_in[4];
  const float* bv    = (const float*)d_in[5];
  const float* wk    = (const float*)d_in[6];
  const float* bk    = (const float*)d_in[7];
  const float* wq    = (const float*)d_in[8];
  const float* bq    = (const float*)d_in[9];
  const float* w1    = (const float*)d_in[10];
  const float* b1    = (const float*)d_in[11];
  const float* w2    = (const float*)d_in[12];
  const float* b2    = (const float*)d_in[13];
  const float* w3    = (const float*)d_in[14];
  const float* b3    = (const float*)d_in[15];
  const float* w4    = (const float*)d_in[16];
  const float* b4    = (const float*)d_in[17];
  _Float16* wt = (_Float16*)d_ws;
  float* out = (float*)d_out;

  prep_w<<<32, 256, 0, stream>>>(enc_w, wt+OFF_ENC, wt+OFF_ENC+8192, NOBS, NHID, NHID);
  prep_w<<<64, 256, 0, stream>>>(wv, wt+OFF_V, wt+OFF_V+16384, NHID, NHID, NHID);
  prep_w<<<64, 256, 0, stream>>>(wk, wt+OFF_K, wt+OFF_K+16384, NHID, NHID, NHID);
  prep_w<<<64, 256, 0, stream>>>(wq, wt+OFF_Q, wt+OFF_Q+16384, NHID, NHID, NHID);
  prep_w<<<64, 256, 0, stream>>>(w1, wt+OFF_W1, wt+OFF_W1+16384, NHID, NHID, NHID);
  prep_w<<<64, 256, 0, stream>>>(w2, wt+OFF_W2, wt+OFF_W2+16384, NHID, NHID, NHID);
  prep_w<<<64, 256, 0, stream>>>(w3, wt+OFF_W3, wt+OFF_W3+16384, NHID, NHID, NHID);
  prep_w<<<8,  256, 0, stream>>>(w4, wt+OFF_W4, wt+OFF_W4+2048, NHID, NACT, 16);

  dgn_main<<<NB, NTHR, 0, stream>>>(x, mask, wt, enc_b, bv, bk, bq,
                                    b1, b2, b3, b4, out);
}

// Round 14
// 164.895 us; speedup vs baseline: 1.0111x; 1.0111x over previous
//
#include <hip/hip_runtime.h>

#define NB   1024
#define NN   128
#define NOBS 64
#define NHID 128
#define NACT 9
#define NTHR 512
#define WLD  136   // padded LDS row stride in halves: conflict-free b128 column reads
#define CVS2 20    // CV row stride in dwords

// workspace offsets (fp16 elements): [hi | lo] per weight, transposed to [dout_pad][din]
#define OFF_ENC 0
#define OFF_V   16384
#define OFF_K   49152
#define OFF_Q   81920
#define OFF_W1  114688
#define OFF_W2  147456
#define OFF_W3  180224
#define OFF_W4  212992

typedef __attribute__((ext_vector_type(8))) _Float16 half8;
typedef __attribute__((ext_vector_type(4))) _Float16 half4v;
typedef __attribute__((ext_vector_type(2))) __fp16 fp16x2;
typedef __attribute__((ext_vector_type(4))) float f32x4;

union H8 { half8 v; fp16x2 p[4]; };
union H4 { half4v v; fp16x2 p[2]; };

// ---------- weight prep: fp16 hi/lo split (RNE), transposed [dout_pad][din] ----------
__global__ void prep_w(const float* __restrict__ w, _Float16* __restrict__ hi,
                       _Float16* __restrict__ lo, int din, int dout, int dpad){
  int i = blockIdx.x * blockDim.x + threadIdx.x;
  if (i >= dpad * din) return;
  int c = i / din, k = i - c * din;
  float v = (c < dout) ? w[(size_t)k * dout + c] : 0.0f;
  _Float16 h = (_Float16)v;
  hi[i] = h;
  lo[i] = (_Float16)(v - (float)h);
}

// ---------- activation split: 8 f32 -> fp16 hi/lo fragments via packed RTZ converts ----------
__device__ __forceinline__ void pack_split8(const float* fv, half8& ah, half8& al){
  H8 A, L;
#pragma unroll
  for (int j = 0; j < 4; ++j){
    fp16x2 h = __builtin_amdgcn_cvt_pkrtz(fv[2*j], fv[2*j+1]);
    float r0 = fv[2*j]   - (float)h[0];
    float r1 = fv[2*j+1] - (float)h[1];
    A.p[j] = h;
    L.p[j] = __builtin_amdgcn_cvt_pkrtz(r0, r1);
  }
  ah = A.v; al = L.v;
}

// ---------- threefry2x32, key = (0, 42) ----------
__device__ __forceinline__ void tf4(unsigned& v0, unsigned& v1, int r0,int r1,int r2,int r3){
  v0 += v1; v1 = (v1<<r0)|(v1>>(32-r0)); v1 ^= v0;
  v0 += v1; v1 = (v1<<r1)|(v1>>(32-r1)); v1 ^= v0;
  v0 += v1; v1 = (v1<<r2)|(v1>>(32-r2)); v1 ^= v0;
  v0 += v1; v1 = (v1<<r3)|(v1>>(32-r3)); v1 ^= v0;
}
__device__ __forceinline__ void threefry(unsigned x0, unsigned x1, unsigned& o0, unsigned& o1){
  const unsigned ks0 = 0u, ks1 = 42u, ks2 = 0x1BD11BDAu ^ 0u ^ 42u;
  unsigned v0 = x0 + ks0, v1 = x1 + ks1;
  tf4(v0,v1,13,15,26,6);  v0 += ks1; v1 += ks2 + 1u;
  tf4(v0,v1,17,29,16,24); v0 += ks2; v1 += ks0 + 2u;
  tf4(v0,v1,13,15,26,6);  v0 += ks0; v1 += ks1 + 3u;
  tf4(v0,v1,17,29,16,24); v0 += ks1; v1 += ks2 + 4u;
  tf4(v0,v1,13,15,26,6);  v0 += ks2; v1 += ks0 + 5u;
  o0 = v0; o1 = v1;
}

#define MFMA(a,b,c) __builtin_amdgcn_mfma_f32_16x16x32_f16((a),(b),(c),0,0,0)
// 3-term split product: ah*bh + al*bh + ah*bl  (al*bl ~ 2^-22, omitted)
#define MFMA3(ah,al,bh,bl,c) do{ (c)=MFMA((ah),(bh),(c)); (c)=MFMA((al),(bh),(c)); \
                                 (c)=MFMA((ah),(bl),(c)); }while(0)

__device__ __forceinline__ void zero8(f32x4* a){
#pragma unroll
  for (int c = 0; c < 8; ++c) a[c] = (f32x4){0.f,0.f,0.f,0.f};
}
// bias preload (coalesced; issued early so latency hides under prior compute)
__device__ __forceinline__ void load_bias8(const float* __restrict__ bias, int l15, float* bb){
#pragma unroll
  for (int c = 0; c < 8; ++c) bb[c] = bias[16*c + l15];
}
// acc init = bias (replaces zero-init + epilogue add)
__device__ __forceinline__ void init8(f32x4* a, const float* bb){
#pragma unroll
  for (int c = 0; c < 8; ++c) a[c] = (f32x4){bb[c], bb[c], bb[c], bb[c]};
}
__device__ __forceinline__ void relu8(f32x4* a){
#pragma unroll
  for (int c = 0; c < 8; ++c)
#pragma unroll
    for (int i = 0; i < 4; ++i) a[c][i] = fmaxf(a[c][i], 0.0f);
}

// ---------- direct stage: global (linear) -> LDS (padded rows) ----------
template<int ROWS, int K>
__device__ __forceinline__ void stage_w(const _Float16* __restrict__ src,
                                        _Float16* dsth, _Float16* dstl, int tid){
  constexpr int GPR = K/8;
  constexpr int NG  = ROWS*GPR;
#pragma unroll
  for (int t0 = 0; t0 < NG; t0 += NTHR){
    int t = t0 + tid;
    if (NG % NTHR != 0 && t >= NG) break;
    int row = t / GPR, gc = t - row*GPR;
    int d = row*WLD + gc*8;
    *(half8*)(dsth + d) = *(const half8*)(src + t*8);
    *(half8*)(dstl + d) = *(const half8*)(src + ROWS*K + t*8);
  }
}

// ---------- async stage: issue global->reg early, write reg->LDS after barrier ----------
template<int NG>
__device__ __forceinline__ void stage_load(const _Float16* __restrict__ src, int loOff,
                                           half8* bh, half8* bl, int tid){
#pragma unroll
  for (int j = 0; j*NTHR < NG; ++j){
    int t = j*NTHR + tid;
    if (NG % NTHR != 0 && t >= NG) break;
    bh[j] = *(const half8*)(src + t*8);
    bl[j] = *(const half8*)(src + loOff + t*8);
  }
}
template<int NG, int GPR>
__device__ __forceinline__ void stage_write(const half8* bh, const half8* bl,
                                            _Float16* dsth, _Float16* dstl, int tid){
#pragma unroll
  for (int j = 0; j*NTHR < NG; ++j){
    int t = j*NTHR + tid;
    if (NG % NTHR != 0 && t >= NG) break;
    int row = t / GPR, gc = t - row*GPR;
    int d = row*WLD + gc*8;
    *(half8*)(dsth + d) = bh[j];
    *(half8*)(dstl + d) = bl[j];
  }
}

// dense GEMM: A-frags in regs, B in LDS padded [rows][WLD] hi/lo; setprio'd MFMA cluster
template<int K>
__device__ __forceinline__ void gemm_lds(const half8* fh, const half8* fl,
                                         const _Float16* SWh, const _Float16* SWl,
                                         f32x4* acc, int g, int l15){
  __builtin_amdgcn_s_setprio(1);
#pragma unroll
  for (int kp = 0; kp < K/32; ++kp){
#pragma unroll
    for (int c = 0; c < 8; ++c){
      const int idx = (16*c + l15)*WLD + (4*kp + g)*8;
      half8 bh = *(const half8*)(SWh + idx);
      half8 bl = *(const half8*)(SWl + idx);
      MFMA3(fh[kp], fl[kp], bh, bl, acc[c]);
    }
  }
  __builtin_amdgcn_s_setprio(0);
}

// acc chunk kp -> this lane's row-major 8 f32 (row l15, cols 8g..8g+7) via wave-private CV
__device__ __forceinline__ void cv_row8(const f32x4* pa, int kp, float* CVf,
                                        int g, int l15, float* fv){
  const int roff = l15*CVS2 + 8*(g & 1);
#pragma unroll
  for (int i = 0; i < 4; ++i) CVf[(4*g+i)*CVS2 + l15] = pa[2*kp][i];
  f32x4 a0 = *(const f32x4*)(CVf + roff);
  f32x4 a1 = *(const f32x4*)(CVf + roff + 4);
#pragma unroll
  for (int i = 0; i < 4; ++i) CVf[(4*g+i)*CVS2 + l15] = pa[2*kp+1][i];
  f32x4 b0 = *(const f32x4*)(CVf + roff);
  f32x4 b1 = *(const f32x4*)(CVf + roff + 4);
  f32x4 f0 = (g < 2) ? a0 : b0;
  f32x4 f1 = (g < 2) ? a1 : b1;
  fv[0]=f0[0]; fv[1]=f0[1]; fv[2]=f0[2]; fv[3]=f0[3];
  fv[4]=f1[0]; fv[5]=f1[1]; fv[6]=f1[2]; fv[7]=f1[3];
}

// full acc -> 4 fragment pairs
__device__ __forceinline__ void conv_all16(const f32x4* pa, float* CVf, int g, int l15,
                                           half8* fh, half8* fl){
#pragma unroll
  for (int kp = 0; kp < 4; ++kp){
    float fv[8];
    cv_row8(pa, kp, CVf, g, l15, fv);
    pack_split8(fv, fh[kp], fl[kp]);
  }
}

// fused conv + GEMM: per kp, convert A chunk then immediately run its 24 MFMAs
__device__ __forceinline__ void gemm_cv(const f32x4* pa, float* CVf,
                                        const _Float16* SWh, const _Float16* SWl,
                                        f32x4* acc, int g, int l15){
#pragma unroll
  for (int kp = 0; kp < 4; ++kp){
    float fv[8];
    cv_row8(pa, kp, CVf, g, l15, fv);
    half8 ah, al;
    pack_split8(fv, ah, al);
    __builtin_amdgcn_s_setprio(1);
#pragma unroll
    for (int c = 0; c < 8; ++c){
      const int idx = (16*c + l15)*WLD + (4*kp + g)*8;
      half8 bh = *(const half8*)(SWh + idx);
      half8 bl = *(const half8*)(SWl + idx);
      MFMA3(ah, al, bh, bl, acc[c]);
    }
    __builtin_amdgcn_s_setprio(0);
  }
}

__global__ void __launch_bounds__(NTHR)
dgn_main(const float* __restrict__ x, const float* __restrict__ mask,
         const _Float16* __restrict__ wt,
         const float* __restrict__ encb, const float* __restrict__ bv,
         const float* __restrict__ bk, const float* __restrict__ bq,
         const float* __restrict__ b1, const float* __restrict__ b2,
         const float* __restrict__ b3, const float* __restrict__ b4,
         float* __restrict__ out){
  // static LDS: 2*34816 + 10240 = 79872 B -> 2 blocks/CU
  __shared__ __align__(16) _Float16 SHh[128*WLD];
  __shared__ __align__(16) _Float16 SHl[128*WLD];
  __shared__ __align__(16) float CVA[8*16*CVS2];

  const int tid  = threadIdx.x;
  const int lane = tid & 63;
  const int w    = tid >> 6;
  const int l15  = lane & 15;
  const int g    = lane >> 4;
  const int b    = blockIdx.x;
  float* CVf = CVA + w*16*CVS2;

  f32x4 accA[8], accB[8];
  half8 wbh[4], wbl[4];   // async weight staging buffer
  float bb[8];            // next-layer bias, preloaded

  // ---- P0: direct stage enc weights; preload enc bias
  load_bias8(encb, l15, bb);
  stage_w<128, 64>(wt + OFF_ENC, SHh, SHl, tid);
  __syncthreads();                                   // B1 enc ready

  // ---- P1: h1 = relu(x @ enc_w + enc_b); prefetch Wq + bq
  init8(accA, bb);
  stage_load<2048>(wt + OFF_Q, 16384, wbh, wbl, tid);
  load_bias8(bq, l15, bb);
  {
    half8 xh[2], xl[2];
    const float* xrow = x + ((size_t)b*NN + w*16 + l15)*NOBS;
#pragma unroll
    for (int kp = 0; kp < 2; ++kp){
      float4 f0 = *(const float4*)(xrow + 32*kp + 8*g);
      float4 f1 = *(const float4*)(xrow + 32*kp + 8*g + 4);
      float fv[8] = {f0.x,f0.y,f0.z,f0.w,f1.x,f1.y,f1.z,f1.w};
      pack_split8(fv, xh[kp], xl[kp]);
    }
    gemm_lds<NOBS>(xh, xl, SHh, SHl, accA, g, l15);
  }
  relu8(accA);
  half8 h1h[4], h1l[4];
  conv_all16(accA, CVf, g, l15, h1h, h1l);           // wave-private CV: safe pre-barrier
  __syncthreads();                                   // B2 enc reads done
  stage_write<2048,16>(wbh, wbl, SHh, SHl, tid);
  __syncthreads();                                   // B3 Wq ready

  // ---- P2: q = relu(h1 @ wq + bq); prefetch Wk + bk
  init8(accA, bb);
  stage_load<2048>(wt + OFF_K, 16384, wbh, wbl, tid);
  load_bias8(bk, l15, bb);
  gemm_lds<NHID>(h1h, h1l, SHh, SHl, accA, g, l15);
  relu8(accA);
  half8 qfh[4], qfl[4];
  conv_all16(accA, CVf, g, l15, qfh, qfl);
  __syncthreads();                                   // B4 Wq reads done
  stage_write<2048,16>(wbh, wbl, SHh, SHl, tid);
  __syncthreads();                                   // B5 Wk ready

  // ---- P3: prefetch mask; k = relu(h1 @ wk + bk) -> split straight into SH
  float mpre[32];
  {
    const float* mbase = mask + (size_t)b*NN*NN;
#pragma unroll
    for (int c = 0; c < 8; ++c)
#pragma unroll
      for (int i = 0; i < 4; ++i)
        mpre[c*4+i] = mbase[(w*16 + 4*g + i)*NN + 16*c + l15];
  }
  init8(accA, bb);
  gemm_lds<NHID>(h1h, h1l, SHh, SHl, accA, g, l15);
  relu8(accA);
  __syncthreads();                                   // B6 Wk reads done (all waves)
#pragma unroll
  for (int c = 0; c < 8; ++c)
#pragma unroll
    for (int i = 0; i < 4; ++i){
      float v = accA[c][i];
      _Float16 kh = (_Float16)v;
      const int idx = (w*16 + 4*g + i)*WLD + 16*c + l15;
      SHh[idx] = kh;
      SHl[idx] = (_Float16)(v - (float)kh);
    }
  __syncthreads();                                   // B7 k staged

  // ---- P4: scores = q @ k^T
  zero8(accB);
  gemm_lds<NHID>(qfh, qfl, SHh, SHl, accB, g, l15);
  __syncthreads();                                   // B8 k reads done

  // ---- P5: mask/clip -> h out, row-softmax, att frags; Wv + bv prefetched under softmax
  half8 afh[4], afl[4];
  {
    float* hbase = out + (size_t)NB*NN + (size_t)b*NN*NN;
    float mx[4] = {-3.0e38f,-3.0e38f,-3.0e38f,-3.0e38f};
#pragma unroll
    for (int c = 0; c < 8; ++c)
#pragma unroll
      for (int i = 0; i < 4; ++i){
        const int row = w*16 + 4*g + i, col = 16*c + l15;
        float m = mpre[c*4+i];
        float hvv = fminf(fmaxf(accB[c][i]*m, 0.0f), 9.0e13f) - 9.0e15f*(1.0f - m);
        hbase[row*NN + col] = hvv;
        accB[c][i] = hvv;
        mx[i] = fmaxf(mx[i], hvv);
      }
    stage_load<2048>(wt + OFF_V, 16384, wbh, wbl, tid);
    load_bias8(bv, l15, bb);
#pragma unroll
    for (int off = 8; off >= 1; off >>= 1)
#pragma unroll
      for (int i = 0; i < 4; ++i) mx[i] = fmaxf(mx[i], __shfl_xor(mx[i], off, 64));
    float sm[4] = {0.f,0.f,0.f,0.f};
#pragma unroll
    for (int c = 0; c < 8; ++c)
#pragma unroll
      for (int i = 0; i < 4; ++i){
        float e = __expf(accB[c][i] - mx[i]);
        accB[c][i] = e; sm[i] += e;
      }
#pragma unroll
    for (int off = 8; off >= 1; off >>= 1)
#pragma unroll
      for (int i = 0; i < 4; ++i) sm[i] += __shfl_xor(sm[i], off, 64);
    float inv[4];
#pragma unroll
    for (int i = 0; i < 4; ++i) inv[i] = 16384.0f / sm[i];  // 2^14 denorm guard
#pragma unroll
    for (int c = 0; c < 8; ++c)
#pragma unroll
      for (int i = 0; i < 4; ++i) accB[c][i] *= inv[i];
    conv_all16(accB, CVf, g, l15, afh, afl);
  }
  stage_write<2048,16>(wbh, wbl, SHh, SHl, tid);
  __syncthreads();                                   // B9 Wv ready

  // ---- P6: v = relu(h1 @ wv + bv); h1 dies
  init8(accA, bb);
  gemm_lds<NHID>(h1h, h1l, SHh, SHl, accA, g, l15);
  relu8(accA);
  __syncthreads();                                   // B10 Wv reads done (all waves)

  // ---- P7: stage vT (transposed, packed converts, b64 stores)
#pragma unroll
  for (int c = 0; c < 8; ++c){
    H4 hp, lp;
#pragma unroll
    for (int j = 0; j < 2; ++j){
      float v0 = accA[c][2*j], v1 = accA[c][2*j+1];
      fp16x2 h = __builtin_amdgcn_cvt_pkrtz(v0, v1);
      hp.p[j] = h;
      lp.p[j] = __builtin_amdgcn_cvt_pkrtz(v0 - (float)h[0], v1 - (float)h[1]);
    }
    const int idx = (16*c + l15)*WLD + w*16 + 4*g;
    *(half4v*)(SHh + idx) = hp.v;
    *(half4v*)(SHl + idx) = lp.v;
  }
  __syncthreads();                                   // B11 vT staged

  // ---- P8: h2 = att @ v (scaled); prefetch W1 + b1
  stage_load<2048>(wt + OFF_W1, 16384, wbh, wbl, tid);
  load_bias8(b1, l15, bb);
  zero8(accB);
  gemm_lds<NHID>(afh, afl, SHh, SHl, accB, g, l15);
#pragma unroll
  for (int c = 0; c < 8; ++c)
#pragma unroll
    for (int i = 0; i < 4; ++i) accB[c][i] *= 6.103515625e-05f;  // 2^-14
  __syncthreads();                                   // B12 vT reads done
  stage_write<2048,16>(wbh, wbl, SHh, SHl, tid);
  __syncthreads();                                   // B13 W1 ready

  // ---- P9: MLP chain, fused conv+gemm, async staging, bias-init accs
  init8(accA, bb);                                   // b1
  stage_load<2048>(wt + OFF_W2, 16384, wbh, wbl, tid);
  load_bias8(b2, l15, bb);
  gemm_cv(accB, CVf, SHh, SHl, accA, g, l15);        // a1 = h2 @ W1 + b1
  relu8(accA);
  __syncthreads();                                   // B14 W1 reads done
  stage_write<2048,16>(wbh, wbl, SHh, SHl, tid);
  __syncthreads();                                   // B15 W2 ready

  init8(accB, bb);                                   // b2
  stage_load<2048>(wt + OFF_W3, 16384, wbh, wbl, tid);
  load_bias8(b3, l15, bb);
  float b4v = (l15 < NACT) ? b4[l15] : 0.0f;
  gemm_cv(accA, CVf, SHh, SHl, accB, g, l15);        // a2 = a1 @ W2 + b2
  relu8(accB);
  __syncthreads();                                   // B16 W2 reads done
  stage_write<2048,16>(wbh, wbl, SHh, SHl, tid);
  __syncthreads();                                   // B17 W3 ready

  init8(accA, bb);                                   // b3
  gemm_cv(accB, CVf, SHh, SHl, accA, g, l15);        // a3 = a2 @ W3 + b3
  relu8(accA);
  // no barrier: W4 is read from global (L2), SH untouched afterwards

  // ---- P10: logits = a3 @ w4 + b4 (W4 direct from L2; fused conv)
  f32x4 la = (f32x4){b4v, b4v, b4v, b4v};
#pragma unroll
  for (int kp = 0; kp < 4; ++kp){
    float fv[8];
    cv_row8(accA, kp, CVf, g, l15, fv);
    half8 ah, al;
    pack_split8(fv, ah, al);
    const int wof = l15*NHID + (4*kp + g)*8;
    half8 bh = *(const half8*)(wt + OFF_W4 + wof);
    half8 bl = *(const half8*)(wt + OFF_W4 + 2048 + wof);
    MFMA3(ah, al, bh, bl, la);
  }
#pragma unroll
  for (int i = 0; i < 4; ++i)
    CVf[(4*g+i)*CVS2 + l15] = la[i];

  // ---- P11: threefry-gumbel + argmax(gumbel + logits), wave-parallel
  // argmax(g + log softmax(L)) == argmax(g + L) (per-row constant shift).
  // Lane (g,l15): row = l15, candidates c = g + 4j (j=0..2, c<9); 2-step shfl reduce.
  {
    const int R = b*NN + w*16 + l15;
    const unsigned HHALF = (unsigned)(NB*NN*NACT/2);  // 589824
    float best = -3.0e38f; int bi = NACT;
#pragma unroll
    for (int j = 0; j < 3; ++j){
      const int c = g + 4*j;
      if (c < NACT){
        float lg = CVf[l15*CVS2 + c];
        unsigned e = (unsigned)(R*NACT + c);
        unsigned c0 = (e < HHALF) ? e : (e - HHALF);
        unsigned o0, o1; threefry(c0, c0 + HHALF, o0, o1);
        unsigned bits = (e < HHALF) ? o0 : o1;
        float u = __uint_as_float((bits >> 9) | 0x3f800000u) - 1.0f;
        float uu = fmaxf(1.17549435e-38f, u + 1.17549435e-38f);
        float gmb = -logf(-logf(uu));
        float scv = gmb + lg;
        if (scv > best){ best = scv; bi = c; }      // within-lane c ascending -> first max
      }
    }
#pragma unroll
    for (int off = 16; off <= 32; off <<= 1){
      float ov = __shfl_xor(best, off, 64);
      int   oi = __shfl_xor(bi,   off, 64);
      if (ov > best || (ov == best && oi < bi)){ best = ov; bi = oi; }
    }
    if (g == 0) out[R] = (float)bi;
  }
}

extern "C" void kernel_launch(void* const* d_in, const int* in_sizes, int n_in,
                              void* d_out, int out_size, void* d_ws, size_t ws_size,
                              hipStream_t stream){
  const float* x     = (const float*)d_in[0];
  const float* mask  = (const float*)d_in[1];
  const float* enc_w = (const float*)d_in[2];
  const float* enc_b = (const float*)d_in[3];
  const float* wv    = (const float*)d_in[4];
  const float* bv    = (const float*)d_in[5];
  const float* wk    = (const float*)d_in[6];
  const float* bk    = (const float*)d_in[7];
  const float* wq    = (const float*)d_in[8];
  const float* bq    = (const float*)d_in[9];
  const float* w1    = (const float*)d_in[10];
  const float* b1    = (const float*)d_in[11];
  const float* w2    = (const float*)d_in[12];
  const float* b2    = (const float*)d_in[13];
  const float* w3    = (const float*)d_in[14];
  const float* b3    = (const float*)d_in[15];
  const float* w4    = (const float*)d_in[16];
  const float* b4    = (const float*)d_in[17];
  _Float16* wt = (_Float16*)d_ws;
  float* out = (float*)d_out;

  prep_w<<<32, 256, 0, stream>>>(enc_w, wt+OFF_ENC, wt+OFF_ENC+8192, NOBS, NHID, NHID);
  prep_w<<<64, 256, 0, stream>>>(wv, wt+OFF_V, wt+OFF_V+16384, NHID, NHID, NHID);
  prep_w<<<64, 256, 0, stream>>>(wk, wt+OFF_K, wt+OFF_K+16384, NHID, NHID, NHID);
  prep_w<<<64, 256, 0, stream>>>(wq, wt+OFF_Q, wt+OFF_Q+16384, NHID, NHID, NHID);
  prep_w<<<64, 256, 0, stream>>>(w1, wt+OFF_W1, wt+OFF_W1+16384, NHID, NHID, NHID);
  prep_w<<<64, 256, 0, stream>>>(w2, wt+OFF_W2, wt+OFF_W2+16384, NHID, NHID, NHID);
  prep_w<<<64, 256, 0, stream>>>(w3, wt+OFF_W3, wt+OFF_W3+16384, NHID, NHID, NHID);
  prep_w<<<8,  256, 0, stream>>>(w4, wt+OFF_W4, wt+OFF_W4+2048, NHID, NACT, 16);

  dgn_main<<<NB, NTHR, 0, stream>>>(x, mask, wt, enc_b, bv, bk, bq,
                                    b1, b2, b3, b4, out);
}

// Round 15
// 149.988 us; speedup vs baseline: 1.1116x; 1.0994x over previous
//
#include <hip/hip_runtime.h>

#define NB   1024
#define NN   128
#define NOBS 64
#define NHID 128
#define NACT 9
#define NTHR 512
#define WLD  136   // padded LDS row stride in halves: conflict-free b128 column reads
#define CVS2 20    // CV row stride in dwords

// workspace offsets (fp16 elements): [hi | lo] per weight, transposed to [dout_pad][din]
#define OFF_ENC 0
#define OFF_V   16384
#define OFF_K   49152
#define OFF_Q   81920
#define OFF_W1  114688
#define OFF_W2  147456
#define OFF_W3  180224
#define OFF_W4  212992

typedef __attribute__((ext_vector_type(8))) _Float16 half8;
typedef __attribute__((ext_vector_type(4))) _Float16 half4v;
typedef __attribute__((ext_vector_type(2))) __fp16 fp16x2;
typedef __attribute__((ext_vector_type(4))) float f32x4;

union H8 { half8 v; fp16x2 p[4]; };
union H4 { half4v v; fp16x2 p[2]; };

// ---------- fused weight prep: ALL weights in ONE launch ----------
// fp16 hi/lo split (RNE), transposed [dout_pad][din]; segment dispatch by flat index.
__global__ void prep_all(const float* __restrict__ enc_w, const float* __restrict__ wv,
                         const float* __restrict__ wk, const float* __restrict__ wq,
                         const float* __restrict__ w1, const float* __restrict__ w2,
                         const float* __restrict__ w3, const float* __restrict__ w4,
                         _Float16* __restrict__ wt){
  int i = blockIdx.x * blockDim.x + threadIdx.x;
  const float* w; int off, sz, dout; bool din64 = false;
  if      (i <   8192){ w = enc_w;             off = OFF_ENC; sz =  8192; dout = 128; din64 = true; }
  else if (i <  24576){ w = wv; i -=   8192;   off = OFF_V;   sz = 16384; dout = 128; }
  else if (i <  40960){ w = wk; i -=  24576;   off = OFF_K;   sz = 16384; dout = 128; }
  else if (i <  57344){ w = wq; i -=  40960;   off = OFF_Q;   sz = 16384; dout = 128; }
  else if (i <  73728){ w = w1; i -=  57344;   off = OFF_W1;  sz = 16384; dout = 128; }
  else if (i <  90112){ w = w2; i -=  73728;   off = OFF_W2;  sz = 16384; dout = 128; }
  else if (i < 106496){ w = w3; i -=  90112;   off = OFF_W3;  sz = 16384; dout = 128; }
  else if (i < 108544){ w = w4; i -= 106496;   off = OFF_W4;  sz =  2048; dout = 9;   }
  else return;
  int c = din64 ? (i >> 6) : (i >> 7);
  int k = din64 ? (i & 63) : (i & 127);
  float v = (c < dout) ? w[(size_t)k * dout + c] : 0.0f;
  _Float16 h = (_Float16)v;
  wt[off + i]      = h;
  wt[off + sz + i] = (_Float16)(v - (float)h);
}

// ---------- activation split: 8 f32 -> fp16 hi/lo fragments via packed RTZ converts ----------
__device__ __forceinline__ void pack_split8(const float* fv, half8& ah, half8& al){
  H8 A, L;
#pragma unroll
  for (int j = 0; j < 4; ++j){
    fp16x2 h = __builtin_amdgcn_cvt_pkrtz(fv[2*j], fv[2*j+1]);
    float r0 = fv[2*j]   - (float)h[0];
    float r1 = fv[2*j+1] - (float)h[1];
    A.p[j] = h;
    L.p[j] = __builtin_amdgcn_cvt_pkrtz(r0, r1);
  }
  ah = A.v; al = L.v;
}

// ---------- threefry2x32, key = (0, 42) ----------
__device__ __forceinline__ void tf4(unsigned& v0, unsigned& v1, int r0,int r1,int r2,int r3){
  v0 += v1; v1 = (v1<<r0)|(v1>>(32-r0)); v1 ^= v0;
  v0 += v1; v1 = (v1<<r1)|(v1>>(32-r1)); v1 ^= v0;
  v0 += v1; v1 = (v1<<r2)|(v1>>(32-r2)); v1 ^= v0;
  v0 += v1; v1 = (v1<<r3)|(v1>>(32-r3)); v1 ^= v0;
}
__device__ __forceinline__ void threefry(unsigned x0, unsigned x1, unsigned& o0, unsigned& o1){
  const unsigned ks0 = 0u, ks1 = 42u, ks2 = 0x1BD11BDAu ^ 0u ^ 42u;
  unsigned v0 = x0 + ks0, v1 = x1 + ks1;
  tf4(v0,v1,13,15,26,6);  v0 += ks1; v1 += ks2 + 1u;
  tf4(v0,v1,17,29,16,24); v0 += ks2; v1 += ks0 + 2u;
  tf4(v0,v1,13,15,26,6);  v0 += ks0; v1 += ks1 + 3u;
  tf4(v0,v1,17,29,16,24); v0 += ks1; v1 += ks2 + 4u;
  tf4(v0,v1,13,15,26,6);  v0 += ks2; v1 += ks0 + 5u;
  o0 = v0; o1 = v1;
}

#define MFMA(a,b,c) __builtin_amdgcn_mfma_f32_16x16x32_f16((a),(b),(c),0,0,0)
// 3-term split product: ah*bh + al*bh + ah*bl  (al*bl ~ 2^-22, omitted)
#define MFMA3(ah,al,bh,bl,c) do{ (c)=MFMA((ah),(bh),(c)); (c)=MFMA((al),(bh),(c)); \
                                 (c)=MFMA((ah),(bl),(c)); }while(0)

__device__ __forceinline__ void zero8(f32x4* a){
#pragma unroll
  for (int c = 0; c < 8; ++c) a[c] = (f32x4){0.f,0.f,0.f,0.f};
}
// bias preload (coalesced; issued early so latency hides under prior compute)
__device__ __forceinline__ void load_bias8(const float* __restrict__ bias, int l15, float* bb){
#pragma unroll
  for (int c = 0; c < 8; ++c) bb[c] = bias[16*c + l15];
}
// acc init = bias (replaces zero-init + epilogue add)
__device__ __forceinline__ void init8(f32x4* a, const float* bb){
#pragma unroll
  for (int c = 0; c < 8; ++c) a[c] = (f32x4){bb[c], bb[c], bb[c], bb[c]};
}
__device__ __forceinline__ void relu8(f32x4* a){
#pragma unroll
  for (int c = 0; c < 8; ++c)
#pragma unroll
    for (int i = 0; i < 4; ++i) a[c][i] = fmaxf(a[c][i], 0.0f);
}

// ---------- direct stage: global (linear) -> LDS (padded rows) ----------
template<int ROWS, int K>
__device__ __forceinline__ void stage_w(const _Float16* __restrict__ src,
                                        _Float16* dsth, _Float16* dstl, int tid){
  constexpr int GPR = K/8;
  constexpr int NG  = ROWS*GPR;
#pragma unroll
  for (int t0 = 0; t0 < NG; t0 += NTHR){
    int t = t0 + tid;
    if (NG % NTHR != 0 && t >= NG) break;
    int row = t / GPR, gc = t - row*GPR;
    int d = row*WLD + gc*8;
    *(half8*)(dsth + d) = *(const half8*)(src + t*8);
    *(half8*)(dstl + d) = *(const half8*)(src + ROWS*K + t*8);
  }
}

// ---------- async stage: issue global->reg early, write reg->LDS after barrier ----------
template<int NG>
__device__ __forceinline__ void stage_load(const _Float16* __restrict__ src, int loOff,
                                           half8* bh, half8* bl, int tid){
#pragma unroll
  for (int j = 0; j*NTHR < NG; ++j){
    int t = j*NTHR + tid;
    if (NG % NTHR != 0 && t >= NG) break;
    bh[j] = *(const half8*)(src + t*8);
    bl[j] = *(const half8*)(src + loOff + t*8);
  }
}
template<int NG, int GPR>
__device__ __forceinline__ void stage_write(const half8* bh, const half8* bl,
                                            _Float16* dsth, _Float16* dstl, int tid){
#pragma unroll
  for (int j = 0; j*NTHR < NG; ++j){
    int t = j*NTHR + tid;
    if (NG % NTHR != 0 && t >= NG) break;
    int row = t / GPR, gc = t - row*GPR;
    int d = row*WLD + gc*8;
    *(half8*)(dsth + d) = bh[j];
    *(half8*)(dstl + d) = bl[j];
  }
}

// dense GEMM: A-frags in regs, B in LDS padded [rows][WLD] hi/lo; setprio'd MFMA cluster
template<int K>
__device__ __forceinline__ void gemm_lds(const half8* fh, const half8* fl,
                                         const _Float16* SWh, const _Float16* SWl,
                                         f32x4* acc, int g, int l15){
  __builtin_amdgcn_s_setprio(1);
#pragma unroll
  for (int kp = 0; kp < K/32; ++kp){
#pragma unroll
    for (int c = 0; c < 8; ++c){
      const int idx = (16*c + l15)*WLD + (4*kp + g)*8;
      half8 bh = *(const half8*)(SWh + idx);
      half8 bl = *(const half8*)(SWl + idx);
      MFMA3(fh[kp], fl[kp], bh, bl, acc[c]);
    }
  }
  __builtin_amdgcn_s_setprio(0);
}

// acc chunk kp -> this lane's row-major 8 f32 (row l15, cols 8g..8g+7) via wave-private CV
__device__ __forceinline__ void cv_row8(const f32x4* pa, int kp, float* CVf,
                                        int g, int l15, float* fv){
  const int roff = l15*CVS2 + 8*(g & 1);
#pragma unroll
  for (int i = 0; i < 4; ++i) CVf[(4*g+i)*CVS2 + l15] = pa[2*kp][i];
  f32x4 a0 = *(const f32x4*)(CVf + roff);
  f32x4 a1 = *(const f32x4*)(CVf + roff + 4);
#pragma unroll
  for (int i = 0; i < 4; ++i) CVf[(4*g+i)*CVS2 + l15] = pa[2*kp+1][i];
  f32x4 b0 = *(const f32x4*)(CVf + roff);
  f32x4 b1 = *(const f32x4*)(CVf + roff + 4);
  f32x4 f0 = (g < 2) ? a0 : b0;
  f32x4 f1 = (g < 2) ? a1 : b1;
  fv[0]=f0[0]; fv[1]=f0[1]; fv[2]=f0[2]; fv[3]=f0[3];
  fv[4]=f1[0]; fv[5]=f1[1]; fv[6]=f1[2]; fv[7]=f1[3];
}

// full acc -> 4 fragment pairs
__device__ __forceinline__ void conv_all16(const f32x4* pa, float* CVf, int g, int l15,
                                           half8* fh, half8* fl){
#pragma unroll
  for (int kp = 0; kp < 4; ++kp){
    float fv[8];
    cv_row8(pa, kp, CVf, g, l15, fv);
    pack_split8(fv, fh[kp], fl[kp]);
  }
}

// fused conv + GEMM: per kp, convert A chunk then immediately run its 24 MFMAs
__device__ __forceinline__ void gemm_cv(const f32x4* pa, float* CVf,
                                        const _Float16* SWh, const _Float16* SWl,
                                        f32x4* acc, int g, int l15){
#pragma unroll
  for (int kp = 0; kp < 4; ++kp){
    float fv[8];
    cv_row8(pa, kp, CVf, g, l15, fv);
    half8 ah, al;
    pack_split8(fv, ah, al);
    __builtin_amdgcn_s_setprio(1);
#pragma unroll
    for (int c = 0; c < 8; ++c){
      const int idx = (16*c + l15)*WLD + (4*kp + g)*8;
      half8 bh = *(const half8*)(SWh + idx);
      half8 bl = *(const half8*)(SWl + idx);
      MFMA3(ah, al, bh, bl, acc[c]);
    }
    __builtin_amdgcn_s_setprio(0);
  }
}

__global__ void __launch_bounds__(NTHR)
dgn_main(const float* __restrict__ x, const float* __restrict__ mask,
         const _Float16* __restrict__ wt,
         const float* __restrict__ encb, const float* __restrict__ bv,
         const float* __restrict__ bk, const float* __restrict__ bq,
         const float* __restrict__ b1, const float* __restrict__ b2,
         const float* __restrict__ b3, const float* __restrict__ b4,
         float* __restrict__ out){
  // static LDS: 2*34816 + 10240 = 79872 B -> 2 blocks/CU
  __shared__ __align__(16) _Float16 SHh[128*WLD];
  __shared__ __align__(16) _Float16 SHl[128*WLD];
  __shared__ __align__(16) float CVA[8*16*CVS2];

  const int tid  = threadIdx.x;
  const int lane = tid & 63;
  const int w    = tid >> 6;
  const int l15  = lane & 15;
  const int g    = lane >> 4;
  const int b    = blockIdx.x;
  float* CVf = CVA + w*16*CVS2;

  f32x4 accA[8], accB[8];
  half8 wbh[4], wbl[4];   // async weight staging buffer
  float bb[8];            // next-layer bias, preloaded

  // ---- P0: direct stage enc weights; preload enc bias
  load_bias8(encb, l15, bb);
  stage_w<128, 64>(wt + OFF_ENC, SHh, SHl, tid);
  __syncthreads();                                   // B1 enc ready

  // ---- P1: h1 = relu(x @ enc_w + enc_b); prefetch Wq + bq
  init8(accA, bb);
  stage_load<2048>(wt + OFF_Q, 16384, wbh, wbl, tid);
  load_bias8(bq, l15, bb);
  {
    half8 xh[2], xl[2];
    const float* xrow = x + ((size_t)b*NN + w*16 + l15)*NOBS;
#pragma unroll
    for (int kp = 0; kp < 2; ++kp){
      float4 f0 = *(const float4*)(xrow + 32*kp + 8*g);
      float4 f1 = *(const float4*)(xrow + 32*kp + 8*g + 4);
      float fv[8] = {f0.x,f0.y,f0.z,f0.w,f1.x,f1.y,f1.z,f1.w};
      pack_split8(fv, xh[kp], xl[kp]);
    }
    gemm_lds<NOBS>(xh, xl, SHh, SHl, accA, g, l15);
  }
  relu8(accA);
  half8 h1h[4], h1l[4];
  conv_all16(accA, CVf, g, l15, h1h, h1l);           // wave-private CV: safe pre-barrier
  __syncthreads();                                   // B2 enc reads done
  stage_write<2048,16>(wbh, wbl, SHh, SHl, tid);
  __syncthreads();                                   // B3 Wq ready

  // ---- P2: q = relu(h1 @ wq + bq); prefetch Wk + bk
  init8(accA, bb);
  stage_load<2048>(wt + OFF_K, 16384, wbh, wbl, tid);
  load_bias8(bk, l15, bb);
  gemm_lds<NHID>(h1h, h1l, SHh, SHl, accA, g, l15);
  relu8(accA);
  half8 qfh[4], qfl[4];
  conv_all16(accA, CVf, g, l15, qfh, qfl);
  __syncthreads();                                   // B4 Wq reads done
  stage_write<2048,16>(wbh, wbl, SHh, SHl, tid);
  __syncthreads();                                   // B5 Wk ready

  // ---- P3: prefetch mask; k = relu(h1 @ wk + bk) -> split straight into SH
  float mpre[32];
  {
    const float* mbase = mask + (size_t)b*NN*NN;
#pragma unroll
    for (int c = 0; c < 8; ++c)
#pragma unroll
      for (int i = 0; i < 4; ++i)
        mpre[c*4+i] = mbase[(w*16 + 4*g + i)*NN + 16*c + l15];
  }
  init8(accA, bb);
  gemm_lds<NHID>(h1h, h1l, SHh, SHl, accA, g, l15);
  relu8(accA);
  __syncthreads();                                   // B6 Wk reads done (all waves)
#pragma unroll
  for (int c = 0; c < 8; ++c)
#pragma unroll
    for (int i = 0; i < 4; ++i){
      float v = accA[c][i];
      _Float16 kh = (_Float16)v;
      const int idx = (w*16 + 4*g + i)*WLD + 16*c + l15;
      SHh[idx] = kh;
      SHl[idx] = (_Float16)(v - (float)kh);
    }
  __syncthreads();                                   // B7 k staged

  // ---- P4: scores = q @ k^T
  zero8(accB);
  gemm_lds<NHID>(qfh, qfl, SHh, SHl, accB, g, l15);
  __syncthreads();                                   // B8 k reads done

  // ---- P5: mask/clip -> h out, row-softmax, att frags; Wv + bv prefetched under softmax
  half8 afh[4], afl[4];
  {
    float* hbase = out + (size_t)NB*NN + (size_t)b*NN*NN;
    float mx[4] = {-3.0e38f,-3.0e38f,-3.0e38f,-3.0e38f};
#pragma unroll
    for (int c = 0; c < 8; ++c)
#pragma unroll
      for (int i = 0; i < 4; ++i){
        const int row = w*16 + 4*g + i, col = 16*c + l15;
        float m = mpre[c*4+i];
        float hvv = fminf(fmaxf(accB[c][i]*m, 0.0f), 9.0e13f) - 9.0e15f*(1.0f - m);
        hbase[row*NN + col] = hvv;
        accB[c][i] = hvv;
        mx[i] = fmaxf(mx[i], hvv);
      }
    stage_load<2048>(wt + OFF_V, 16384, wbh, wbl, tid);
    load_bias8(bv, l15, bb);
#pragma unroll
    for (int off = 8; off >= 1; off >>= 1)
#pragma unroll
      for (int i = 0; i < 4; ++i) mx[i] = fmaxf(mx[i], __shfl_xor(mx[i], off, 64));
    float sm[4] = {0.f,0.f,0.f,0.f};
#pragma unroll
    for (int c = 0; c < 8; ++c)
#pragma unroll
      for (int i = 0; i < 4; ++i){
        float e = __expf(accB[c][i] - mx[i]);
        accB[c][i] = e; sm[i] += e;
      }
#pragma unroll
    for (int off = 8; off >= 1; off >>= 1)
#pragma unroll
      for (int i = 0; i < 4; ++i) sm[i] += __shfl_xor(sm[i], off, 64);
    float inv[4];
#pragma unroll
    for (int i = 0; i < 4; ++i) inv[i] = 16384.0f / sm[i];  // 2^14 denorm guard
#pragma unroll
    for (int c = 0; c < 8; ++c)
#pragma unroll
      for (int i = 0; i < 4; ++i) accB[c][i] *= inv[i];
    conv_all16(accB, CVf, g, l15, afh, afl);
  }
  stage_write<2048,16>(wbh, wbl, SHh, SHl, tid);
  __syncthreads();                                   // B9 Wv ready

  // ---- P6: v = relu(h1 @ wv + bv); h1 dies
  init8(accA, bb);
  gemm_lds<NHID>(h1h, h1l, SHh, SHl, accA, g, l15);
  relu8(accA);
  __syncthreads();                                   // B10 Wv reads done (all waves)

  // ---- P7: stage vT (transposed, packed converts, b64 stores)
#pragma unroll
  for (int c = 0; c < 8; ++c){
    H4 hp, lp;
#pragma unroll
    for (int j = 0; j < 2; ++j){
      float v0 = accA[c][2*j], v1 = accA[c][2*j+1];
      fp16x2 h = __builtin_amdgcn_cvt_pkrtz(v0, v1);
      hp.p[j] = h;
      lp.p[j] = __builtin_amdgcn_cvt_pkrtz(v0 - (float)h[0], v1 - (float)h[1]);
    }
    const int idx = (16*c + l15)*WLD + w*16 + 4*g;
    *(half4v*)(SHh + idx) = hp.v;
    *(half4v*)(SHl + idx) = lp.v;
  }
  __syncthreads();                                   // B11 vT staged

  // ---- P8: h2 = att @ v (scaled); prefetch W1 + b1
  stage_load<2048>(wt + OFF_W1, 16384, wbh, wbl, tid);
  load_bias8(b1, l15, bb);
  zero8(accB);
  gemm_lds<NHID>(afh, afl, SHh, SHl, accB, g, l15);
#pragma unroll
  for (int c = 0; c < 8; ++c)
#pragma unroll
    for (int i = 0; i < 4; ++i) accB[c][i] *= 6.103515625e-05f;  // 2^-14
  __syncthreads();                                   // B12 vT reads done
  stage_write<2048,16>(wbh, wbl, SHh, SHl, tid);
  __syncthreads();                                   // B13 W1 ready

  // ---- P9: MLP chain, fused conv+gemm, async staging, bias-init accs
  init8(accA, bb);                                   // b1
  stage_load<2048>(wt + OFF_W2, 16384, wbh, wbl, tid);
  load_bias8(b2, l15, bb);
  gemm_cv(accB, CVf, SHh, SHl, accA, g, l15);        // a1 = h2 @ W1 + b1
  relu8(accA);
  __syncthreads();                                   // B14 W1 reads done
  stage_write<2048,16>(wbh, wbl, SHh, SHl, tid);
  __syncthreads();                                   // B15 W2 ready

  init8(accB, bb);                                   // b2
  stage_load<2048>(wt + OFF_W3, 16384, wbh, wbl, tid);
  load_bias8(b3, l15, bb);
  float b4v = (l15 < NACT) ? b4[l15] : 0.0f;
  gemm_cv(accA, CVf, SHh, SHl, accB, g, l15);        // a2 = a1 @ W2 + b2
  relu8(accB);
  __syncthreads();                                   // B16 W2 reads done
  stage_write<2048,16>(wbh, wbl, SHh, SHl, tid);
  __syncthreads();                                   // B17 W3 ready

  init8(accA, bb);                                   // b3
  gemm_cv(accB, CVf, SHh, SHl, accA, g, l15);        // a3 = a2 @ W3 + b3
  relu8(accA);
  // no barrier: W4 is read from global (L2), SH untouched afterwards

  // ---- P10: logits = a3 @ w4 + b4 (W4 direct from L2; fused conv)
  f32x4 la = (f32x4){b4v, b4v, b4v, b4v};
#pragma unroll
  for (int kp = 0; kp < 4; ++kp){
    float fv[8];
    cv_row8(accA, kp, CVf, g, l15, fv);
    half8 ah, al;
    pack_split8(fv, ah, al);
    const int wof = l15*NHID + (4*kp + g)*8;
    half8 bh = *(const half8*)(wt + OFF_W4 + wof);
    half8 bl = *(const half8*)(wt + OFF_W4 + 2048 + wof);
    MFMA3(ah, al, bh, bl, la);
  }
#pragma unroll
  for (int i = 0; i < 4; ++i)
    CVf[(4*g+i)*CVS2 + l15] = la[i];

  // ---- P11: threefry-gumbel + argmax(gumbel + logits), wave-parallel
  // argmax(g + log softmax(L)) == argmax(g + L) (per-row constant shift).
  // Lane (g,l15): row = l15, candidates c = g + 4j (j=0..2, c<9); 2-step shfl reduce.
  {
    const int R = b*NN + w*16 + l15;
    const unsigned HHALF = (unsigned)(NB*NN*NACT/2);  // 589824
    float best = -3.0e38f; int bi = NACT;
#pragma unroll
    for (int j = 0; j < 3; ++j){
      const int c = g + 4*j;
      if (c < NACT){
        float lg = CVf[l15*CVS2 + c];
        unsigned e = (unsigned)(R*NACT + c);
        unsigned c0 = (e < HHALF) ? e : (e - HHALF);
        unsigned o0, o1; threefry(c0, c0 + HHALF, o0, o1);
        unsigned bits = (e < HHALF) ? o0 : o1;
        float u = __uint_as_float((bits >> 9) | 0x3f800000u) - 1.0f;
        float uu = fmaxf(1.17549435e-38f, u + 1.17549435e-38f);
        float gmb = -logf(-logf(uu));
        float scv = gmb + lg;
        if (scv > best){ best = scv; bi = c; }      // within-lane c ascending -> first max
      }
    }
#pragma unroll
    for (int off = 16; off <= 32; off <<= 1){
      float ov = __shfl_xor(best, off, 64);
      int   oi = __shfl_xor(bi,   off, 64);
      if (ov > best || (ov == best && oi < bi)){ best = ov; bi = oi; }
    }
    if (g == 0) out[R] = (float)bi;
  }
}

extern "C" void kernel_launch(void* const* d_in, const int* in_sizes, int n_in,
                              void* d_out, int out_size, void* d_ws, size_t ws_size,
                              hipStream_t stream){
  const float* x     = (const float*)d_in[0];
  const float* mask  = (const float*)d_in[1];
  const float* enc_w = (const float*)d_in[2];
  const float* enc_b = (const float*)d_in[3];
  const float* wv    = (const float*)d_in[4];
  const float* bv    = (const float*)d_in[5];
  const float* wk    = (const float*)d_in[6];
  const float* bk    = (const float*)d_in[7];
  const float* wq    = (const float*)d_in[8];
  const float* bq    = (const float*)d_in[9];
  const float* w1    = (const float*)d_in[10];
  const float* b1    = (const float*)d_in[11];
  const float* w2    = (const float*)d_in[12];
  const float* b2    = (const float*)d_in[13];
  const float* w3    = (const float*)d_in[14];
  const float* b3    = (const float*)d_in[15];
  const float* w4    = (const float*)d_in[16];
  const float* b4    = (const float*)d_in[17];
  _Float16* wt = (_Float16*)d_ws;
  float* out = (float*)d_out;

  // single fused prep launch: 108544 elements total -> 424 blocks x 256
  prep_all<<<424, 256, 0, stream>>>(enc_w, wv, wk, wq, w1, w2, w3, w4, wt);

  dgn_main<<<NB, NTHR, 0, stream>>>(x, mask, wt, enc_b, bv, bk, bq,
                                    b1, b2, b3, b4, out);
}